// Round 20
// baseline (412.765 us; speedup 1.0000x reference)
//
#include <hip/hip_runtime.h>
#include <hip/hip_bf16.h>
#include <math.h>

#define DIM 1024
#define NHEADS 16
#define HD 64
#define TT 2048
#define BB 4
#define MTOK (BB*TT)
#define HID 4096

typedef __attribute__((ext_vector_type(8))) short bf16x8;
typedef __attribute__((ext_vector_type(4))) float f32x4;
typedef unsigned short u16;
typedef unsigned int u32;

__device__ inline u16 f2b(float f){
  __hip_bfloat16 h = __float2bfloat16(f);
  return __builtin_bit_cast(u16, h);
}
__device__ inline float b2f(u16 u){
  __hip_bfloat16 h = __builtin_bit_cast(__hip_bfloat16, u);
  return __bfloat162float(h);
}

__device__ inline u32 cvtpk(float lo, float hi_){
  u32 r;
  asm("v_cvt_pk_bf16_f32 %0, %1, %2" : "=v"(r) : "v"(lo), "v"(hi_));
  return r;
}

__device__ inline void load_lds16(const void* g, void* l){
  __builtin_amdgcn_global_load_lds(
      (const __attribute__((address_space(1))) void*)g,
      (__attribute__((address_space(3))) void*)l,
      16, 0, 0);
}

// ---------------- weight transpose + f32->bf16 convert: Wt[n][k] = W[k][n]
__global__ __launch_bounds__(256) void wconv_t(const float* __restrict__ W,
                                               u16* __restrict__ Wt, int K, int N){
  __shared__ float tl[32][33];
  const int k0 = blockIdx.x*32, n0 = blockIdx.y*32;
  const int tx = threadIdx.x & 31, ty = threadIdx.x >> 5; // 32 x 8
  #pragma unroll
  for (int r=0;r<32;r+=8)
    tl[ty+r][tx] = W[(size_t)(k0+ty+r)*N + (n0+tx)];
  __syncthreads();
  #pragma unroll
  for (int r=0;r<32;r+=8)
    Wt[(size_t)(n0+ty+r)*K + (k0+tx)] = f2b(tl[tx][ty+r]);
}

// ---------------- layernorm: f32 or bf16 in -> bf16 out
template<bool BF16IN>
__global__ __launch_bounds__(256) void ln_fwd(const float* __restrict__ xf,
                                              const u16* __restrict__ xh,
                                              const float* __restrict__ g,
                                              const float* __restrict__ bta,
                                              u16* __restrict__ out){
  const int row = blockIdx.x, t = threadIdx.x;
  float4 v;
  if constexpr (BF16IN){
    const ushort4 u = ((const ushort4*)(xh + (size_t)row*DIM))[t];
    v.x = b2f(u.x); v.y = b2f(u.y); v.z = b2f(u.z); v.w = b2f(u.w);
  } else {
    v = ((const float4*)(xf + (size_t)row*DIM))[t];
  }
  float s  = v.x+v.y+v.z+v.w;
  float s2 = v.x*v.x+v.y*v.y+v.z*v.z+v.w*v.w;
  #pragma unroll
  for (int m=1;m<64;m<<=1){ s += __shfl_xor(s,m); s2 += __shfl_xor(s2,m); }
  __shared__ float red[8];
  if ((t&63)==0){ red[t>>6]=s; red[4+(t>>6)]=s2; }
  __syncthreads();
  s  = red[0]+red[1]+red[2]+red[3];
  s2 = red[4]+red[5]+red[6]+red[7];
  const float mu = s*(1.0f/DIM);
  const float rstd = rsqrtf(s2*(1.0f/DIM) - mu*mu + 1e-5f);
  const float4 gv = ((const float4*)g)[t];
  const float4 bv = ((const float4*)bta)[t];
  ushort4 ov;
  ov.x = f2b((v.x-mu)*rstd*gv.x + bv.x);
  ov.y = f2b((v.y-mu)*rstd*gv.y + bv.y);
  ov.z = f2b((v.z-mu)*rstd*gv.z + bv.z);
  ov.w = f2b((v.w-mu)*rstd*gv.w + bv.w);
  ((ushort4*)out)[(size_t)row*(DIM/4) + t] = ov;
}

// ---------------- 128x128 GEMM, 256 thr / 4 waves (2x2), wave tile 64x64.
// TBUF: BK=32 triple-buffer, depth-2 prefetch, counted vmcnt(4).
// XCD mapping: EPI0/2 (wide N): xcd owns m-rows, lid sweeps rows per column
//              (A-panel <= 2.1MB L2-resident).
//              EPI1/3 (N=1024, 8 col-tiles): xcd owns ONE n-column strip
//              (B-panel 0.25-1MB L2-resident; A rows streamed once from L3).
// EPI 0: qkv split (bounce);  EPI 1: +resid(f32) -> bf16 x2h (bounce);
// EPI 2: gelu -> outh HID (bounce);  EPI 3: +resid(bf16) -> f32 out (direct).
template<int EPI>
__global__ __launch_bounds__(256) void gemm_bt(
    const u16* __restrict__ A, const u16* __restrict__ Bt,
    const float* __restrict__ bias, const float* __restrict__ resid,
    const u16* __restrict__ residh,
    float* __restrict__ outf, u16* __restrict__ outh,
    u16* __restrict__ qo, u16* __restrict__ ko, u16* __restrict__ vo,
    int M, int N, int K)
{
  __shared__ __align__(16) u16 smem[24576];   // 3 x (A 8KB | B 8KB); Ct reuses 32KB
  u16* Ct = smem;
  const int t = threadIdx.x, wv = t>>6, ln = t&63;
  const int nbx = gridDim.x, nby = gridDim.y;
  const int bid = blockIdx.y*nbx + blockIdx.x;
  const int xcd = bid & 7, lid = bid >> 3;
  int m0, n0;
  if constexpr (EPI==1 || EPI==3){
    // nbx == 8: xcd owns one n-column strip; lid sweeps all m-rows
    n0 = xcd * 128;
    m0 = lid * 128;
  } else {
    const int rpx = nby >> 3;               // m-rows per XCD
    m0 = (xcd*rpx + (lid % rpx)) * 128;
    n0 = (lid / rpx) * 128;
  }
  const int wr = wv>>1, wc = wv&1;
  const int hi = ln>>4, lr = hi*4, lc = ln&15;
  f32x4 acc[4][4] = {};

  auto STAGE32 = [&](int buf, int kt){
    u16* As = smem + buf*8192;
    u16* Bs = smem + buf*8192 + 4096;
    #pragma unroll
    for (int j=0;j<2;j++){
      const int id = j*256 + t;        // 0..511 16B chunks
      const int row = id>>2, c = id&3;
      const int cs = c ^ ((row>>1)&3); // inverse read-swizzle
      load_lds16(A  + (size_t)(m0+row)*K + kt + cs*8, (char*)As + id*16);
      load_lds16(Bt + (size_t)(n0+row)*K + kt + cs*8, (char*)Bs + id*16);
    }
  };
  auto RD32 = [&](const u16* base, int r)->bf16x8{
    return *(const bf16x8*)(base + r*32 + ((hi ^ ((r>>1)&3))<<3));
  };
  auto COMPUTE32 = [&](int buf){
    const u16* As = smem + buf*8192;
    const u16* Bs = smem + buf*8192 + 4096;
    bf16x8 af[4], bfr[4];
    #pragma unroll
    for (int mi=0;mi<4;mi++) af[mi] = RD32(As, wr*64 + mi*16 + lc);
    #pragma unroll
    for (int ni=0;ni<4;ni++) bfr[ni] = RD32(Bs, wc*64 + ni*16 + lc);
    __builtin_amdgcn_s_setprio(1);
    #pragma unroll
    for (int mi=0;mi<4;mi++)
      #pragma unroll
      for (int ni=0;ni<4;ni++)
        acc[mi][ni] = __builtin_amdgcn_mfma_f32_16x16x32_bf16(af[mi], bfr[ni], acc[mi][ni], 0,0,0);
    __builtin_amdgcn_s_setprio(0);
  };

  const int nk = K>>5;
  STAGE32(0, 0);
  STAGE32(1, 32);
  asm volatile("s_waitcnt vmcnt(4)" ::: "memory");
  __builtin_amdgcn_s_barrier();
  for (int tt=0; tt<nk; ++tt){
    if (tt+2 < nk) STAGE32((tt+2)%3, (tt+2)<<5);
    COMPUTE32(tt%3);
    if (tt+1 < nk){
      if (tt+2 < nk) asm volatile("s_waitcnt vmcnt(4)" ::: "memory");
      else           asm volatile("s_waitcnt vmcnt(0)" ::: "memory");
      __builtin_amdgcn_s_barrier();
    }
  }

  if constexpr (EPI==3){
    // direct f32 stores, residual from bf16 buffer
    #pragma unroll
    for (int ni=0;ni<4;ni++){
      const int gn = n0 + wc*64 + ni*16 + lc;
      const float bv = bias[gn];
      #pragma unroll
      for (int mi=0;mi<4;mi++){
        const int gmb = m0 + wr*64 + mi*16 + lr;
        f32x4 a = acc[mi][ni];
        #pragma unroll
        for (int i=0;i<4;i++){
          const size_t idx = (size_t)(gmb+i)*DIM + gn;
          outf[idx] = a[i] + bv + b2f(residh[idx]);
        }
      }
    }
  } else {
    const int part = (EPI==0) ? (n0>>10) : 0;
    __syncthreads();   // frag reads done before Ct overwrites buffers
    #pragma unroll
    for (int ni=0;ni<4;ni++){
      const int gn = n0 + wc*64 + ni*16 + lc;
      const float bv = bias[gn];
      const int cl = wc*64 + ni*16 + lc;
      #pragma unroll
      for (int mi=0;mi<4;mi++){
        f32x4 a = acc[mi][ni];
        #pragma unroll
        for (int i=0;i<4;i++){
          const int rl = wr*64 + mi*16 + lr + i;
          float val = a[i] + bv;
          if constexpr (EPI==2){
            const float xx = val*val;
            const float w  = val * fmaf(xx, 0.10294322f, 2.30220781f);
            const float y  = exp2f(w);
            const float r_ = __builtin_amdgcn_rcpf(1.0f + y);
            val = val - val*r_;
          } else if constexpr (EPI==1){
            val += resid[(size_t)(m0+rl)*DIM + gn];
          }
          int r = rl, c = cl;
          if (EPI==0 && part==2){ r = cl; c = rl; }
          const int chunk = c>>3;
          const int csw = (chunk&8) | ((chunk ^ (r&7)) & 7);
          Ct[(r<<7) + (csw<<3) + (c&7)] = f2b(val);
        }
      }
    }
    __syncthreads();
    const int cid = t & 7, rsub = t >> 3;
    const int bb = m0>>11, tok0b = m0&2047;
    const int h0 = (EPI==0) ? ((n0&1023)>>6) : 0;
    #pragma unroll
    for (int pass=0; pass<4; ++pass){
      const int rr = pass*32 + rsub;
      #pragma unroll
      for (int hh=0; hh<2; ++hh){
        const int chunk = hh*8 + cid;
        const int sw = (chunk&8) | ((chunk ^ (rr&7)) & 7);
        const bf16x8 vvv = *(const bf16x8*)&Ct[(rr<<7) + (sw<<3)];
        if constexpr (EPI==2){
          *(bf16x8*)&outh[(size_t)(m0+rr)*HID + n0 + chunk*8] = vvv;
        } else if constexpr (EPI==1){
          *(bf16x8*)&outh[(size_t)(m0+rr)*DIM + n0 + chunk*8] = vvv;
        } else {
          if (part==2){
            const int head = h0 + (rr>>6), d = rr&63;
            *(bf16x8*)&vo[(((size_t)bb*NHEADS + head)*HD + d)*TT + tok0b + chunk*8] = vvv;
          } else {
            u16* dst = part ? ko : qo;
            const int head = h0 + hh;
            *(bf16x8*)&dst[(((size_t)bb*NHEADS + head)*TT + tok0b + rr)*HD + cid*8] = vvv;
          }
        }
      }
    }
  }
}

// ---------------- causal flash attention: paired q-strips (qb, 15-qb) per block,
// 8 waves x 16 rows per strip, shared K/V staging, TRIPLE-buffer depth-2 prefetch
// with counted vmcnt(2), swizzled LDS, in-register P (cvt_pk + shfl),
// row-sum via MFMA ones. vtb is [B,H,hd,T].
__global__ __launch_bounds__(512) void attn_fwd(
    const u16* __restrict__ qpt, const u16* __restrict__ kb, const u16* __restrict__ vtb,
    u16* __restrict__ o)
{
  __shared__ __align__(16) u16 Kd[3][64*64];
  __shared__ __align__(16) u16 Vd[3][64*64];
  const int t = threadIdx.x, wv = t>>6, ln = t&63;
  const int bid  = blockIdx.y*gridDim.x + blockIdx.x;      // 0..511
  const int orig = (bid&7)*64 + (bid>>3);
  const int bh   = orig>>3;
  const int qp   = orig&7;
  const int qbA  = qp, qbB = 15-qp;
  const size_t base = (size_t)bh*TT*HD;
  const int hi = ln>>4, lc = ln&15;
  const int ntA = 2*qbA + 2, ntB = 2*qbB + 2;   // ntB >= 18
  const int qbaseA = qbA*128 + wv*16, qrowA = qbaseA + lc;
  const int qbaseB = qbB*128 + wv*16, qrowB = qbaseB + lc;

  const bf16x8 qfA0 = *(const bf16x8*)(qpt + base + (size_t)qrowA*HD + hi*8);
  const bf16x8 qfA1 = *(const bf16x8*)(qpt + base + (size_t)qrowA*HD + 32 + hi*8);
  const bf16x8 qfB0 = *(const bf16x8*)(qpt + base + (size_t)qrowB*HD + hi*8);
  const bf16x8 qfB1 = *(const bf16x8*)(qpt + base + (size_t)qrowB*HD + 32 + hi*8);
  f32x4 oaccA[4] = {}, oaccB[4] = {};
  f32x4 lsumA = {0.f,0.f,0.f,0.f}, lsumB = {0.f,0.f,0.f,0.f};
  float mrunA = -1e30f, mrunB = -1e30f;
  const float SCQ = 0.125f * 1.44269504f;
  bf16x8 ones;
  #pragma unroll
  for (int j=0;j<8;j++) ones[j] = (short)0x3F80;

  const int srow = t>>3;
  const int sch  = t&7;
  const int gch  = (sch ^ (srow&7))<<3;

  auto STAGE = [&](int nb, int kt){
    load_lds16(kb  + base + (size_t)(kt*64+srow)*HD + gch, &Kd[nb][srow*64 + sch*8]);
    load_lds16(vtb + base + (size_t)srow*TT + kt*64 + gch, &Vd[nb][srow*64 + sch*8]);
  };
  auto FRAG = [&](const u16* buf, int r, int ch)->bf16x8{
    return *(const bf16x8*)(buf + r*64 + ((ch ^ (r&7))<<3));
  };
  const int src0 = ((ln&16)<<1) + lc;
  const int src1 = src0 + 16;
  auto pick = [&](u32 w0, u32 w1, int src)->u32{
    const u32 a = (u32)__shfl((int)w0, src);
    const u32 b = (u32)__shfl((int)w1, src);
    return (hi<2) ? a : b;
  };

  auto strip_tile = [&](int kt, const u16* Kb, const u16* Vb,
                        const bf16x8& qf0, const bf16x8& qf1,
                        int qbase, int qrow,
                        f32x4* oacc, f32x4& lsum, float& mrun){
    if (kt*64 > qbase + 15) return;
    float sv[4][4];
    __builtin_amdgcn_s_setprio(1);
    #pragma unroll
    for (int cf=0;cf<4;cf++){
      const int r = cf*16 + lc;
      const bf16x8 kf0 = FRAG(Kb, r, hi);
      const bf16x8 kf1 = FRAG(Kb, r, hi+4);
      f32x4 z = {0.f,0.f,0.f,0.f};
      z = __builtin_amdgcn_mfma_f32_16x16x32_bf16(kf0, qf0, z, 0,0,0);
      z = __builtin_amdgcn_mfma_f32_16x16x32_bf16(kf1, qf1, z, 0,0,0);
      sv[cf][0]=z[0]; sv[cf][1]=z[1]; sv[cf][2]=z[2]; sv[cf][3]=z[3];
    }
    __builtin_amdgcn_s_setprio(0);
    float mx = -1e30f;
    if (kt*64 + 63 > qbase){
      #pragma unroll
      for (int cf=0;cf<4;cf++)
        #pragma unroll
        for (int i=0;i<4;i++){
          const int kvg = kt*64 + cf*16 + 4*hi + i;
          float s_ = sv[cf][i]*SCQ;
          s_ = (kvg > qrow) ? -1e30f : s_;
          sv[cf][i] = s_;
          mx = fmaxf(mx, s_);
        }
    } else {
      #pragma unroll
      for (int cf=0;cf<4;cf++)
        #pragma unroll
        for (int i=0;i<4;i++){
          const float s_ = sv[cf][i]*SCQ;
          sv[cf][i] = s_;
          mx = fmaxf(mx, s_);
        }
    }
    mx = fmaxf(mx, __shfl_xor(mx, 16));
    mx = fmaxf(mx, __shfl_xor(mx, 32));
    if (__any(mx > mrun + 11.0f)){
      const float mnew = fmaxf(mrun, mx);
      const float sc = exp2f(mrun - mnew);
      mrun = mnew;
      const float s0 = __shfl(sc, 4*hi+0);
      const float s1 = __shfl(sc, 4*hi+1);
      const float s2 = __shfl(sc, 4*hi+2);
      const float s3 = __shfl(sc, 4*hi+3);
      #pragma unroll
      for (int df=0;df<4;df++){
        oacc[df][0] *= s0; oacc[df][1] *= s1;
        oacc[df][2] *= s2; oacc[df][3] *= s3;
      }
      lsum[0] *= s0; lsum[1] *= s1; lsum[2] *= s2; lsum[3] *= s3;
    }
    u32 W[4][2];
    #pragma unroll
    for (int cf=0;cf<4;cf++){
      const float e0 = exp2f(sv[cf][0] - mrun);
      const float e1 = exp2f(sv[cf][1] - mrun);
      const float e2 = exp2f(sv[cf][2] - mrun);
      const float e3 = exp2f(sv[cf][3] - mrun);
      W[cf][0] = cvtpk(e0, e1);
      W[cf][1] = cvtpk(e2, e3);
    }
    uint4 uA, uB;
    uA.x = pick(W[0][0], W[1][0], src0);
    uA.y = pick(W[0][1], W[1][1], src0);
    uA.z = pick(W[0][0], W[1][0], src1);
    uA.w = pick(W[0][1], W[1][1], src1);
    uB.x = pick(W[2][0], W[3][0], src0);
    uB.y = pick(W[2][1], W[3][1], src0);
    uB.z = pick(W[2][0], W[3][0], src1);
    uB.w = pick(W[2][1], W[3][1], src1);
    const bf16x8 paA = __builtin_bit_cast(bf16x8, uA);
    const bf16x8 paB = __builtin_bit_cast(bf16x8, uB);
    __builtin_amdgcn_s_setprio(1);
    #pragma unroll
    for (int df=0;df<4;df++){
      const bf16x8 v0 = FRAG(Vb, df*16+lc, hi);
      const bf16x8 v1 = FRAG(Vb, df*16+lc, hi+4);
      oacc[df] = __builtin_amdgcn_mfma_f32_16x16x32_bf16(paA, v0, oacc[df], 0,0,0);
      oacc[df] = __builtin_amdgcn_mfma_f32_16x16x32_bf16(paB, v1, oacc[df], 0,0,0);
    }
    lsum = __builtin_amdgcn_mfma_f32_16x16x32_bf16(paA, ones, lsum, 0,0,0);
    lsum = __builtin_amdgcn_mfma_f32_16x16x32_bf16(paB, ones, lsum, 0,0,0);
    __builtin_amdgcn_s_setprio(0);
  };

  // prologue: stage tiles 0,1; wait tile0 (tile1 stays in flight)
  STAGE(0, 0);
  STAGE(1, 1);
  asm volatile("s_waitcnt vmcnt(2)" ::: "memory");
  __syncthreads();

  for (int kt=0; kt<ntB; kt++){
    if (kt+2 < ntB) STAGE((kt+2)%3, kt+2);
    const u16* Kb = Kd[kt%3];
    const u16* Vb = Vd[kt%3];
    strip_tile(kt, Kb, Vb, qfB0, qfB1, qbaseB, qrowB, oaccB, lsumB, mrunB);
    if (kt < ntA)
      strip_tile(kt, Kb, Vb, qfA0, qfA1, qbaseA, qrowA, oaccA, lsumA, mrunA);
    if (kt+1 < ntB){
      if (kt+2 < ntB) asm volatile("s_waitcnt vmcnt(2)" ::: "memory");
      else            asm volatile("s_waitcnt vmcnt(0)" ::: "memory");
      __syncthreads();
    }
  }

  const int b = bh>>4, h = bh&15;
  {
    const float inv[4] = {1.0f/lsumA[0], 1.0f/lsumA[1], 1.0f/lsumA[2], 1.0f/lsumA[3]};
    const int qg0 = qbaseA + 4*hi;
    #pragma unroll
    for (int i=0;i<4;i++){
      const size_t rowb = ((size_t)b*TT + (size_t)(qg0 + i))*DIM + h*HD;
      #pragma unroll
      for (int df=0;df<4;df++)
        o[rowb + df*16 + lc] = f2b(oaccA[df][i]*inv[i]);
    }
  }
  {
    const float inv[4] = {1.0f/lsumB[0], 1.0f/lsumB[1], 1.0f/lsumB[2], 1.0f/lsumB[3]};
    const int qg0 = qbaseB + 4*hi;
    #pragma unroll
    for (int i=0;i<4;i++){
      const size_t rowb = ((size_t)b*TT + (size_t)(qg0 + i))*DIM + h*HD;
      #pragma unroll
      for (int df=0;df<4;df++)
        o[rowb + df*16 + lc] = f2b(oaccB[df][i]*inv[i]);
    }
  }
}

extern "C" void kernel_launch(void* const* d_in, const int* in_sizes, int n_in,
                              void* d_out, int out_size, void* d_ws, size_t ws_size,
                              hipStream_t stream){
  (void)in_sizes; (void)n_in; (void)out_size; (void)ws_size;
  const float* x     = (const float*)d_in[0];
  const float* ln1g  = (const float*)d_in[1];
  const float* ln1b  = (const float*)d_in[2];
  const float* qkvw  = (const float*)d_in[3];
  const float* qkvb  = (const float*)d_in[4];
  const float* projw = (const float*)d_in[5];
  const float* projb = (const float*)d_in[6];
  const float* ln2g  = (const float*)d_in[7];
  const float* ln2b  = (const float*)d_in[8];
  const float* ff1w  = (const float*)d_in[9];
  const float* ff1b  = (const float*)d_in[10];
  const float* ff2w  = (const float*)d_in[11];
  const float* ff2b  = (const float*)d_in[12];
  float* out = (float*)d_out;

  char* ws = (char*)d_ws;
  size_t off = 0;
  auto alloc = [&](size_t n){ char* p = ws + off; off += (n + 255) & ~(size_t)255; return p; };
  u16* wqkvt  = (u16*)alloc((size_t)3072*1024*2);
  u16* wprojt = (u16*)alloc((size_t)1024*1024*2);
  u16* wff1t  = (u16*)alloc((size_t)4096*1024*2);
  u16* wff2t  = (u16*)alloc((size_t)1024*4096*2);
  u16* h1     = (u16*)alloc((size_t)MTOK*DIM*2);
  u16* qbuf   = (u16*)alloc((size_t)MTOK*DIM*2);
  u16* kbuf   = (u16*)alloc((size_t)MTOK*DIM*2);
  u16* vbuf   = (u16*)alloc((size_t)MTOK*DIM*2);   // [B,H,hd,T]
  u16* aout   = (u16*)alloc((size_t)MTOK*DIM*2);
  u16* x2h    = (u16*)alloc((size_t)MTOK*DIM*2);   // bf16 mid-residual
  u16* h2     = (u16*)alloc((size_t)MTOK*DIM*2);
  u16* act    = (u16*)alloc((size_t)MTOK*HID*2);

  wconv_t<<<dim3(1024/32, 3072/32), 256, 0, stream>>>(qkvw, wqkvt, 1024, 3072);
  wconv_t<<<dim3(1024/32, 1024/32), 256, 0, stream>>>(projw, wprojt, 1024, 1024);
  wconv_t<<<dim3(1024/32, 4096/32), 256, 0, stream>>>(ff1w, wff1t, 1024, 4096);
  wconv_t<<<dim3(4096/32, 1024/32), 256, 0, stream>>>(ff2w, wff2t, 4096, 1024);

  ln_fwd<false><<<MTOK, 256, 0, stream>>>(x, nullptr, ln1g, ln1b, h1);

  gemm_bt<0><<<dim3(3072/128, MTOK/128), 256, 0, stream>>>(
      h1, wqkvt, qkvb, nullptr, nullptr, nullptr, nullptr, qbuf, kbuf, vbuf, MTOK, 3072, 1024);

  attn_fwd<<<dim3(8, BB*NHEADS), 512, 0, stream>>>(qbuf, kbuf, vbuf, aout);

  gemm_bt<1><<<dim3(1024/128, MTOK/128), 256, 0, stream>>>(
      aout, wprojt, projb, x, nullptr, nullptr, x2h, nullptr, nullptr, nullptr, MTOK, 1024, 1024);

  ln_fwd<true><<<MTOK, 256, 0, stream>>>(nullptr, x2h, ln2g, ln2b, h2);

  gemm_bt<2><<<dim3(4096/128, MTOK/128), 256, 0, stream>>>(
      h2, wff1t, ff1b, nullptr, nullptr, nullptr, act, nullptr, nullptr, nullptr, MTOK, HID, 1024);

  gemm_bt<3><<<dim3(1024/128, MTOK/128), 256, 0, stream>>>(
      act, wff2t, ff2b, nullptr, x2h, out, nullptr, nullptr, nullptr, nullptr, MTOK, DIM, HID);
}

// Round 21
// 394.843 us; speedup vs baseline: 1.0454x; 1.0454x over previous
//
#include <hip/hip_runtime.h>
#include <hip/hip_bf16.h>
#include <math.h>

#define DIM 1024
#define NHEADS 16
#define HD 64
#define TT 2048
#define BB 4
#define MTOK (BB*TT)
#define HID 4096

typedef __attribute__((ext_vector_type(8))) short bf16x8;
typedef __attribute__((ext_vector_type(4))) float f32x4;
typedef unsigned short u16;
typedef unsigned int u32;

__device__ inline u16 f2b(float f){
  __hip_bfloat16 h = __float2bfloat16(f);
  return __builtin_bit_cast(u16, h);
}
__device__ inline float b2f(u16 u){
  __hip_bfloat16 h = __builtin_bit_cast(__hip_bfloat16, u);
  return __bfloat162float(h);
}

__device__ inline u32 cvtpk(float lo, float hi_){
  u32 r;
  asm("v_cvt_pk_bf16_f32 %0, %1, %2" : "=v"(r) : "v"(lo), "v"(hi_));
  return r;
}

__device__ inline void load_lds16(const void* g, void* l){
  __builtin_amdgcn_global_load_lds(
      (const __attribute__((address_space(1))) void*)g,
      (__attribute__((address_space(3))) void*)l,
      16, 0, 0);
}

// ---------------- weight transpose + f32->bf16 convert: Wt[n][k] = W[k][n]
__global__ __launch_bounds__(256) void wconv_t(const float* __restrict__ W,
                                               u16* __restrict__ Wt, int K, int N){
  __shared__ float tl[32][33];
  const int k0 = blockIdx.x*32, n0 = blockIdx.y*32;
  const int tx = threadIdx.x & 31, ty = threadIdx.x >> 5; // 32 x 8
  #pragma unroll
  for (int r=0;r<32;r+=8)
    tl[ty+r][tx] = W[(size_t)(k0+ty+r)*N + (n0+tx)];
  __syncthreads();
  #pragma unroll
  for (int r=0;r<32;r+=8)
    Wt[(size_t)(n0+ty+r)*K + (k0+tx)] = f2b(tl[tx][ty+r]);
}

// ---------------- layernorm: f32 or bf16 in -> bf16 out
template<bool BF16IN>
__global__ __launch_bounds__(256) void ln_fwd(const float* __restrict__ xf,
                                              const u16* __restrict__ xh,
                                              const float* __restrict__ g,
                                              const float* __restrict__ bta,
                                              u16* __restrict__ out){
  const int row = blockIdx.x, t = threadIdx.x;
  float4 v;
  if constexpr (BF16IN){
    const ushort4 u = ((const ushort4*)(xh + (size_t)row*DIM))[t];
    v.x = b2f(u.x); v.y = b2f(u.y); v.z = b2f(u.z); v.w = b2f(u.w);
  } else {
    v = ((const float4*)(xf + (size_t)row*DIM))[t];
  }
  float s  = v.x+v.y+v.z+v.w;
  float s2 = v.x*v.x+v.y*v.y+v.z*v.z+v.w*v.w;
  #pragma unroll
  for (int m=1;m<64;m<<=1){ s += __shfl_xor(s,m); s2 += __shfl_xor(s2,m); }
  __shared__ float red[8];
  if ((t&63)==0){ red[t>>6]=s; red[4+(t>>6)]=s2; }
  __syncthreads();
  s  = red[0]+red[1]+red[2]+red[3];
  s2 = red[4]+red[5]+red[6]+red[7];
  const float mu = s*(1.0f/DIM);
  const float rstd = rsqrtf(s2*(1.0f/DIM) - mu*mu + 1e-5f);
  const float4 gv = ((const float4*)g)[t];
  const float4 bv = ((const float4*)bta)[t];
  ushort4 ov;
  ov.x = f2b((v.x-mu)*rstd*gv.x + bv.x);
  ov.y = f2b((v.y-mu)*rstd*gv.y + bv.y);
  ov.z = f2b((v.z-mu)*rstd*gv.z + bv.z);
  ov.w = f2b((v.w-mu)*rstd*gv.w + bv.w);
  ((ushort4*)out)[(size_t)row*(DIM/4) + t] = ov;
}

// ---------------- 128x128 GEMM, 256 thr / 4 waves (2x2), wave tile 64x64.
// TBUF: BK=32 triple-buffer, depth-2 prefetch, counted vmcnt(4).
// XCD mapping: xcd owns m-rows [xcd*rpx,(xcd+1)*rpx); lid sweeps rows per column.
// EPI 0: qkv split (bounce);  EPI 1: +resid(f32) -> bf16 x2h (bounce);
// EPI 2: gelu -> outh HID (bounce);  EPI 3: +resid(bf16) -> f32 out (direct).
template<int EPI>
__global__ __launch_bounds__(256) void gemm_bt(
    const u16* __restrict__ A, const u16* __restrict__ Bt,
    const float* __restrict__ bias, const float* __restrict__ resid,
    const u16* __restrict__ residh,
    float* __restrict__ outf, u16* __restrict__ outh,
    u16* __restrict__ qo, u16* __restrict__ ko, u16* __restrict__ vo,
    int M, int N, int K)
{
  __shared__ __align__(16) u16 smem[24576];   // 3 x (A 8KB | B 8KB); Ct reuses 32KB
  u16* Ct = smem;
  const int t = threadIdx.x, wv = t>>6, ln = t&63;
  const int nbx = gridDim.x, nby = gridDim.y;
  const int bid = blockIdx.y*nbx + blockIdx.x;
  const int xcd = bid & 7, lid = bid >> 3;
  const int rpx = nby >> 3;                 // m-rows per XCD
  const int m0 = (xcd*rpx + (lid % rpx)) * 128;
  const int n0 = (lid / rpx) * 128;
  const int wr = wv>>1, wc = wv&1;
  const int hi = ln>>4, lr = hi*4, lc = ln&15;
  f32x4 acc[4][4] = {};

  auto STAGE32 = [&](int buf, int kt){
    u16* As = smem + buf*8192;
    u16* Bs = smem + buf*8192 + 4096;
    #pragma unroll
    for (int j=0;j<2;j++){
      const int id = j*256 + t;        // 0..511 16B chunks
      const int row = id>>2, c = id&3;
      const int cs = c ^ ((row>>1)&3); // inverse read-swizzle
      load_lds16(A  + (size_t)(m0+row)*K + kt + cs*8, (char*)As + id*16);
      load_lds16(Bt + (size_t)(n0+row)*K + kt + cs*8, (char*)Bs + id*16);
    }
  };
  auto RD32 = [&](const u16* base, int r)->bf16x8{
    return *(const bf16x8*)(base + r*32 + ((hi ^ ((r>>1)&3))<<3));
  };
  auto COMPUTE32 = [&](int buf){
    const u16* As = smem + buf*8192;
    const u16* Bs = smem + buf*8192 + 4096;
    bf16x8 af[4], bfr[4];
    #pragma unroll
    for (int mi=0;mi<4;mi++) af[mi] = RD32(As, wr*64 + mi*16 + lc);
    #pragma unroll
    for (int ni=0;ni<4;ni++) bfr[ni] = RD32(Bs, wc*64 + ni*16 + lc);
    __builtin_amdgcn_s_setprio(1);
    #pragma unroll
    for (int mi=0;mi<4;mi++)
      #pragma unroll
      for (int ni=0;ni<4;ni++)
        acc[mi][ni] = __builtin_amdgcn_mfma_f32_16x16x32_bf16(af[mi], bfr[ni], acc[mi][ni], 0,0,0);
    __builtin_amdgcn_s_setprio(0);
  };

  const int nk = K>>5;
  STAGE32(0, 0);
  STAGE32(1, 32);
  asm volatile("s_waitcnt vmcnt(4)" ::: "memory");
  __builtin_amdgcn_s_barrier();
  for (int tt=0; tt<nk; ++tt){
    if (tt+2 < nk) STAGE32((tt+2)%3, (tt+2)<<5);
    COMPUTE32(tt%3);
    if (tt+1 < nk){
      if (tt+2 < nk) asm volatile("s_waitcnt vmcnt(4)" ::: "memory");
      else           asm volatile("s_waitcnt vmcnt(0)" ::: "memory");
      __builtin_amdgcn_s_barrier();
    }
  }

  if constexpr (EPI==3){
    // direct f32 stores, residual from bf16 buffer
    #pragma unroll
    for (int ni=0;ni<4;ni++){
      const int gn = n0 + wc*64 + ni*16 + lc;
      const float bv = bias[gn];
      #pragma unroll
      for (int mi=0;mi<4;mi++){
        const int gmb = m0 + wr*64 + mi*16 + lr;
        f32x4 a = acc[mi][ni];
        #pragma unroll
        for (int i=0;i<4;i++){
          const size_t idx = (size_t)(gmb+i)*DIM + gn;
          outf[idx] = a[i] + bv + b2f(residh[idx]);
        }
      }
    }
  } else {
    const int part = (EPI==0) ? (n0>>10) : 0;
    __syncthreads();   // frag reads done before Ct overwrites buffers
    #pragma unroll
    for (int ni=0;ni<4;ni++){
      const int gn = n0 + wc*64 + ni*16 + lc;
      const float bv = bias[gn];
      const int cl = wc*64 + ni*16 + lc;
      #pragma unroll
      for (int mi=0;mi<4;mi++){
        f32x4 a = acc[mi][ni];
        #pragma unroll
        for (int i=0;i<4;i++){
          const int rl = wr*64 + mi*16 + lr + i;
          float val = a[i] + bv;
          if constexpr (EPI==2){
            const float xx = val*val;
            const float w  = val * fmaf(xx, 0.10294322f, 2.30220781f);
            const float y  = exp2f(w);
            const float r_ = __builtin_amdgcn_rcpf(1.0f + y);
            val = val - val*r_;
          } else if constexpr (EPI==1){
            val += resid[(size_t)(m0+rl)*DIM + gn];
          }
          int r = rl, c = cl;
          if (EPI==0 && part==2){ r = cl; c = rl; }
          const int chunk = c>>3;
          const int csw = (chunk&8) | ((chunk ^ (r&7)) & 7);
          Ct[(r<<7) + (csw<<3) + (c&7)] = f2b(val);
        }
      }
    }
    __syncthreads();
    const int cid = t & 7, rsub = t >> 3;
    const int bb = m0>>11, tok0b = m0&2047;
    const int h0 = (EPI==0) ? ((n0&1023)>>6) : 0;
    #pragma unroll
    for (int pass=0; pass<4; ++pass){
      const int rr = pass*32 + rsub;
      #pragma unroll
      for (int hh=0; hh<2; ++hh){
        const int chunk = hh*8 + cid;
        const int sw = (chunk&8) | ((chunk ^ (rr&7)) & 7);
        const bf16x8 vvv = *(const bf16x8*)&Ct[(rr<<7) + (sw<<3)];
        if constexpr (EPI==2){
          *(bf16x8*)&outh[(size_t)(m0+rr)*HID + n0 + chunk*8] = vvv;
        } else if constexpr (EPI==1){
          *(bf16x8*)&outh[(size_t)(m0+rr)*DIM + n0 + chunk*8] = vvv;
        } else {
          if (part==2){
            const int head = h0 + (rr>>6), d = rr&63;
            *(bf16x8*)&vo[(((size_t)bb*NHEADS + head)*HD + d)*TT + tok0b + chunk*8] = vvv;
          } else {
            u16* dst = part ? ko : qo;
            const int head = h0 + hh;
            *(bf16x8*)&dst[(((size_t)bb*NHEADS + head)*TT + tok0b + rr)*HD + cid*8] = vvv;
          }
        }
      }
    }
  }
}

// ---------------- causal flash attention: paired q-strips (qb, 15-qb) per block,
// 8 waves x 16 rows per strip, shared K/V staging, TRIPLE-buffer depth-2 prefetch
// with counted vmcnt(2), swizzled LDS, in-register P (cvt_pk + shfl),
// row-sum via MFMA ones. vtb is [B,H,hd,T].
__global__ __launch_bounds__(512) void attn_fwd(
    const u16* __restrict__ qpt, const u16* __restrict__ kb, const u16* __restrict__ vtb,
    u16* __restrict__ o)
{
  __shared__ __align__(16) u16 Kd[3][64*64];
  __shared__ __align__(16) u16 Vd[3][64*64];
  const int t = threadIdx.x, wv = t>>6, ln = t&63;
  const int bid  = blockIdx.y*gridDim.x + blockIdx.x;      // 0..511
  const int orig = (bid&7)*64 + (bid>>3);
  const int bh   = orig>>3;
  const int qp   = orig&7;
  const int qbA  = qp, qbB = 15-qp;
  const size_t base = (size_t)bh*TT*HD;
  const int hi = ln>>4, lc = ln&15;
  const int ntA = 2*qbA + 2, ntB = 2*qbB + 2;   // ntB >= 18
  const int qbaseA = qbA*128 + wv*16, qrowA = qbaseA + lc;
  const int qbaseB = qbB*128 + wv*16, qrowB = qbaseB + lc;

  const bf16x8 qfA0 = *(const bf16x8*)(qpt + base + (size_t)qrowA*HD + hi*8);
  const bf16x8 qfA1 = *(const bf16x8*)(qpt + base + (size_t)qrowA*HD + 32 + hi*8);
  const bf16x8 qfB0 = *(const bf16x8*)(qpt + base + (size_t)qrowB*HD + hi*8);
  const bf16x8 qfB1 = *(const bf16x8*)(qpt + base + (size_t)qrowB*HD + 32 + hi*8);
  f32x4 oaccA[4] = {}, oaccB[4] = {};
  f32x4 lsumA = {0.f,0.f,0.f,0.f}, lsumB = {0.f,0.f,0.f,0.f};
  float mrunA = -1e30f, mrunB = -1e30f;
  const float SCQ = 0.125f * 1.44269504f;
  bf16x8 ones;
  #pragma unroll
  for (int j=0;j<8;j++) ones[j] = (short)0x3F80;

  const int srow = t>>3;
  const int sch  = t&7;
  const int gch  = (sch ^ (srow&7))<<3;

  auto STAGE = [&](int nb, int kt){
    load_lds16(kb  + base + (size_t)(kt*64+srow)*HD + gch, &Kd[nb][srow*64 + sch*8]);
    load_lds16(vtb + base + (size_t)srow*TT + kt*64 + gch, &Vd[nb][srow*64 + sch*8]);
  };
  auto FRAG = [&](const u16* buf, int r, int ch)->bf16x8{
    return *(const bf16x8*)(buf + r*64 + ((ch ^ (r&7))<<3));
  };
  const int src0 = ((ln&16)<<1) + lc;
  const int src1 = src0 + 16;
  auto pick = [&](u32 w0, u32 w1, int src)->u32{
    const u32 a = (u32)__shfl((int)w0, src);
    const u32 b = (u32)__shfl((int)w1, src);
    return (hi<2) ? a : b;
  };

  auto strip_tile = [&](int kt, const u16* Kb, const u16* Vb,
                        const bf16x8& qf0, const bf16x8& qf1,
                        int qbase, int qrow,
                        f32x4* oacc, f32x4& lsum, float& mrun){
    if (kt*64 > qbase + 15) return;
    float sv[4][4];
    __builtin_amdgcn_s_setprio(1);
    #pragma unroll
    for (int cf=0;cf<4;cf++){
      const int r = cf*16 + lc;
      const bf16x8 kf0 = FRAG(Kb, r, hi);
      const bf16x8 kf1 = FRAG(Kb, r, hi+4);
      f32x4 z = {0.f,0.f,0.f,0.f};
      z = __builtin_amdgcn_mfma_f32_16x16x32_bf16(kf0, qf0, z, 0,0,0);
      z = __builtin_amdgcn_mfma_f32_16x16x32_bf16(kf1, qf1, z, 0,0,0);
      sv[cf][0]=z[0]; sv[cf][1]=z[1]; sv[cf][2]=z[2]; sv[cf][3]=z[3];
    }
    __builtin_amdgcn_s_setprio(0);
    float mx = -1e30f;
    if (kt*64 + 63 > qbase){
      #pragma unroll
      for (int cf=0;cf<4;cf++)
        #pragma unroll
        for (int i=0;i<4;i++){
          const int kvg = kt*64 + cf*16 + 4*hi + i;
          float s_ = sv[cf][i]*SCQ;
          s_ = (kvg > qrow) ? -1e30f : s_;
          sv[cf][i] = s_;
          mx = fmaxf(mx, s_);
        }
    } else {
      #pragma unroll
      for (int cf=0;cf<4;cf++)
        #pragma unroll
        for (int i=0;i<4;i++){
          const float s_ = sv[cf][i]*SCQ;
          sv[cf][i] = s_;
          mx = fmaxf(mx, s_);
        }
    }
    mx = fmaxf(mx, __shfl_xor(mx, 16));
    mx = fmaxf(mx, __shfl_xor(mx, 32));
    if (__any(mx > mrun + 11.0f)){
      const float mnew = fmaxf(mrun, mx);
      const float sc = exp2f(mrun - mnew);
      mrun = mnew;
      const float s0 = __shfl(sc, 4*hi+0);
      const float s1 = __shfl(sc, 4*hi+1);
      const float s2 = __shfl(sc, 4*hi+2);
      const float s3 = __shfl(sc, 4*hi+3);
      #pragma unroll
      for (int df=0;df<4;df++){
        oacc[df][0] *= s0; oacc[df][1] *= s1;
        oacc[df][2] *= s2; oacc[df][3] *= s3;
      }
      lsum[0] *= s0; lsum[1] *= s1; lsum[2] *= s2; lsum[3] *= s3;
    }
    u32 W[4][2];
    #pragma unroll
    for (int cf=0;cf<4;cf++){
      const float e0 = exp2f(sv[cf][0] - mrun);
      const float e1 = exp2f(sv[cf][1] - mrun);
      const float e2 = exp2f(sv[cf][2] - mrun);
      const float e3 = exp2f(sv[cf][3] - mrun);
      W[cf][0] = cvtpk(e0, e1);
      W[cf][1] = cvtpk(e2, e3);
    }
    uint4 uA, uB;
    uA.x = pick(W[0][0], W[1][0], src0);
    uA.y = pick(W[0][1], W[1][1], src0);
    uA.z = pick(W[0][0], W[1][0], src1);
    uA.w = pick(W[0][1], W[1][1], src1);
    uB.x = pick(W[2][0], W[3][0], src0);
    uB.y = pick(W[2][1], W[3][1], src0);
    uB.z = pick(W[2][0], W[3][0], src1);
    uB.w = pick(W[2][1], W[3][1], src1);
    const bf16x8 paA = __builtin_bit_cast(bf16x8, uA);
    const bf16x8 paB = __builtin_bit_cast(bf16x8, uB);
    __builtin_amdgcn_s_setprio(1);
    #pragma unroll
    for (int df=0;df<4;df++){
      const bf16x8 v0 = FRAG(Vb, df*16+lc, hi);
      const bf16x8 v1 = FRAG(Vb, df*16+lc, hi+4);
      oacc[df] = __builtin_amdgcn_mfma_f32_16x16x32_bf16(paA, v0, oacc[df], 0,0,0);
      oacc[df] = __builtin_amdgcn_mfma_f32_16x16x32_bf16(paB, v1, oacc[df], 0,0,0);
    }
    lsum = __builtin_amdgcn_mfma_f32_16x16x32_bf16(paA, ones, lsum, 0,0,0);
    lsum = __builtin_amdgcn_mfma_f32_16x16x32_bf16(paB, ones, lsum, 0,0,0);
    __builtin_amdgcn_s_setprio(0);
  };

  // prologue: stage tiles 0,1; wait tile0 (tile1 stays in flight)
  STAGE(0, 0);
  STAGE(1, 1);
  asm volatile("s_waitcnt vmcnt(2)" ::: "memory");
  __syncthreads();

  for (int kt=0; kt<ntB; kt++){
    if (kt+2 < ntB) STAGE((kt+2)%3, kt+2);
    const u16* Kb = Kd[kt%3];
    const u16* Vb = Vd[kt%3];
    strip_tile(kt, Kb, Vb, qfB0, qfB1, qbaseB, qrowB, oaccB, lsumB, mrunB);
    if (kt < ntA)
      strip_tile(kt, Kb, Vb, qfA0, qfA1, qbaseA, qrowA, oaccA, lsumA, mrunA);
    if (kt+1 < ntB){
      if (kt+2 < ntB) asm volatile("s_waitcnt vmcnt(2)" ::: "memory");
      else            asm volatile("s_waitcnt vmcnt(0)" ::: "memory");
      __syncthreads();
    }
  }

  const int b = bh>>4, h = bh&15;
  {
    const float inv[4] = {1.0f/lsumA[0], 1.0f/lsumA[1], 1.0f/lsumA[2], 1.0f/lsumA[3]};
    const int qg0 = qbaseA + 4*hi;
    #pragma unroll
    for (int i=0;i<4;i++){
      const size_t rowb = ((size_t)b*TT + (size_t)(qg0 + i))*DIM + h*HD;
      #pragma unroll
      for (int df=0;df<4;df++)
        o[rowb + df*16 + lc] = f2b(oaccA[df][i]*inv[i]);
    }
  }
  {
    const float inv[4] = {1.0f/lsumB[0], 1.0f/lsumB[1], 1.0f/lsumB[2], 1.0f/lsumB[3]};
    const int qg0 = qbaseB + 4*hi;
    #pragma unroll
    for (int i=0;i<4;i++){
      const size_t rowb = ((size_t)b*TT + (size_t)(qg0 + i))*DIM + h*HD;
      #pragma unroll
      for (int df=0;df<4;df++)
        o[rowb + df*16 + lc] = f2b(oaccB[df][i]*inv[i]);
    }
  }
}

extern "C" void kernel_launch(void* const* d_in, const int* in_sizes, int n_in,
                              void* d_out, int out_size, void* d_ws, size_t ws_size,
                              hipStream_t stream){
  (void)in_sizes; (void)n_in; (void)out_size; (void)ws_size;
  const float* x     = (const float*)d_in[0];
  const float* ln1g  = (const float*)d_in[1];
  const float* ln1b  = (const float*)d_in[2];
  const float* qkvw  = (const float*)d_in[3];
  const float* qkvb  = (const float*)d_in[4];
  const float* projw = (const float*)d_in[5];
  const float* projb = (const float*)d_in[6];
  const float* ln2g  = (const float*)d_in[7];
  const float* ln2b  = (const float*)d_in[8];
  const float* ff1w  = (const float*)d_in[9];
  const float* ff1b  = (const float*)d_in[10];
  const float* ff2w  = (const float*)d_in[11];
  const float* ff2b  = (const float*)d_in[12];
  float* out = (float*)d_out;

  char* ws = (char*)d_ws;
  size_t off = 0;
  auto alloc = [&](size_t n){ char* p = ws + off; off += (n + 255) & ~(size_t)255; return p; };
  u16* wqkvt  = (u16*)alloc((size_t)3072*1024*2);
  u16* wprojt = (u16*)alloc((size_t)1024*1024*2);
  u16* wff1t  = (u16*)alloc((size_t)4096*1024*2);
  u16* wff2t  = (u16*)alloc((size_t)1024*4096*2);
  u16* h1     = (u16*)alloc((size_t)MTOK*DIM*2);
  u16* qbuf   = (u16*)alloc((size_t)MTOK*DIM*2);
  u16* kbuf   = (u16*)alloc((size_t)MTOK*DIM*2);
  u16* vbuf   = (u16*)alloc((size_t)MTOK*DIM*2);   // [B,H,hd,T]
  u16* aout   = (u16*)alloc((size_t)MTOK*DIM*2);
  u16* x2h    = (u16*)alloc((size_t)MTOK*DIM*2);   // bf16 mid-residual
  u16* h2     = (u16*)alloc((size_t)MTOK*DIM*2);
  u16* act    = (u16*)alloc((size_t)MTOK*HID*2);

  wconv_t<<<dim3(1024/32, 3072/32), 256, 0, stream>>>(qkvw, wqkvt, 1024, 3072);
  wconv_t<<<dim3(1024/32, 1024/32), 256, 0, stream>>>(projw, wprojt, 1024, 1024);
  wconv_t<<<dim3(1024/32, 4096/32), 256, 0, stream>>>(ff1w, wff1t, 1024, 4096);
  wconv_t<<<dim3(4096/32, 1024/32), 256, 0, stream>>>(ff2w, wff2t, 4096, 1024);

  ln_fwd<false><<<MTOK, 256, 0, stream>>>(x, nullptr, ln1g, ln1b, h1);

  gemm_bt<0><<<dim3(3072/128, MTOK/128), 256, 0, stream>>>(
      h1, wqkvt, qkvb, nullptr, nullptr, nullptr, nullptr, qbuf, kbuf, vbuf, MTOK, 3072, 1024);

  attn_fwd<<<dim3(8, BB*NHEADS), 512, 0, stream>>>(qbuf, kbuf, vbuf, aout);

  gemm_bt<1><<<dim3(1024/128, MTOK/128), 256, 0, stream>>>(
      aout, wprojt, projb, x, nullptr, nullptr, x2h, nullptr, nullptr, nullptr, MTOK, 1024, 1024);

  ln_fwd<true><<<MTOK, 256, 0, stream>>>(nullptr, x2h, ln2g, ln2b, h2);

  gemm_bt<2><<<dim3(4096/128, MTOK/128), 256, 0, stream>>>(
      h2, wff1t, ff1b, nullptr, nullptr, nullptr, act, nullptr, nullptr, nullptr, MTOK, HID, 1024);

  gemm_bt<3><<<dim3(1024/128, MTOK/128), 256, 0, stream>>>(
      act, wff2t, ff2b, nullptr, x2h, out, nullptr, nullptr, nullptr, nullptr, MTOK, DIM, HID);
}